// Round 14
// baseline (505.897 us; speedup 1.0000x reference)
//
#include <hip/hip_runtime.h>
#include <hip/hip_fp16.h>

#define N_NODES 200000
#define F_IN 128
#define HID 16
#define SHIFT 7
#define BKT_NODES 128              // 1 << SHIFT
#define NB 1563                    // ceil(N_NODES / 128)
#define CAPB 4608                  // per-bucket capacity: mean 4096 + 8 sigma
#define OF_CAP 65536               // overflow list capacity
#define PART_BLOCKS 2048
#define AGG_T 512
#define NGRP (AGG_T / 16)          // 32 node-groups per pass
#define NPASS (BKT_NODES / NGRP)   // 4

// ---- non-temporal load helpers (pure streaming reads) ----------------------
__device__ __forceinline__ int ldnt_i(const int* p) {
    return __builtin_nontemporal_load(p);
}
__device__ __forceinline__ float ldnt_f(const float* p) {
    return __builtin_nontemporal_load(p);
}

// ---------------- Stage 1: h = x @ W1 -> fp16 [N,16] -----------------------
__global__ __launch_bounds__(256) void gemm1_kernel(const float* __restrict__ x,
                                                    const float* __restrict__ W1,
                                                    __half* __restrict__ h) {
    __shared__ float w[F_IN * HID];  // 8 KB
    int tid = threadIdx.x;
    for (int i = tid; i < F_IN * HID; i += 256) w[i] = W1[i];
    __syncthreads();

    int row = blockIdx.x * 256 + tid;
    if (row >= N_NODES) return;

    float acc[HID];
#pragma unroll
    for (int j = 0; j < HID; j++) acc[j] = 0.f;

    const float4* xr = reinterpret_cast<const float4*>(x + (size_t)row * F_IN);
#pragma unroll 4
    for (int k4 = 0; k4 < F_IN / 4; k4++) {
        float4 xv = xr[k4];
        const float* wr = &w[k4 * 4 * HID];
#pragma unroll
        for (int j = 0; j < HID; j++) acc[j] += xv.x * wr[j];
#pragma unroll
        for (int j = 0; j < HID; j++) acc[j] += xv.y * wr[HID + j];
#pragma unroll
        for (int j = 0; j < HID; j++) acc[j] += xv.z * wr[2 * HID + j];
#pragma unroll
        for (int j = 0; j < HID; j++) acc[j] += xv.w * wr[3 * HID + j];
    }

    union { __half hh[16]; uint4 u[2]; } pk;
#pragma unroll
    for (int j = 0; j < HID; j++) pk.hh[j] = __float2half(acc[j]);
    uint4* hr = reinterpret_cast<uint4*>(h + (size_t)row * HID);
    hr[0] = pk.u[0];
    hr[1] = pk.u[1];
}

// ---------------- Partition: global bump allocation -------------------------
// One shared cursor per bucket (padded to a 64B line). All blocks append to
// the same per-bucket segment -> lines fill fast -> ~1x write amplification.
// record: {src | local_dst<<18, weight_bits}
__global__ __launch_bounds__(256) void partition_kernel(const int* __restrict__ src,
                                                        const int* __restrict__ dst,
                                                        const float* __restrict__ ew,
                                                        int* __restrict__ cnt_pad,
                                                        int* __restrict__ n_of,
                                                        int4* __restrict__ ofr,
                                                        int2* __restrict__ recs,
                                                        int n_edges) {
    int stride = gridDim.x * 256;
    for (int e = blockIdx.x * 256 + threadIdx.x; e < n_edges; e += stride) {
        int d = ldnt_i(&dst[e]);
        int s = ldnt_i(&src[e]);
        float w = ldnt_f(&ew[e]);
        int b = d >> SHIFT;
        int pos = atomicAdd(&cnt_pad[b * 16], 1);   // one counter per 64B line
        if (pos < CAPB) {
            recs[(size_t)b * CAPB + pos] =
                make_int2(s | ((d & (BKT_NODES - 1)) << 18), __float_as_int(w));
        } else {
            int of = atomicAdd(n_of, 1);
            if (of < OF_CAP) ofr[of] = make_int4(s, d, __float_as_int(w), 0);
        }
    }
}

// ---------------- Aggregation: in-LDS counting sort + register acc ----------
// One block per bucket (R6-verified engine; single chunk since CAPB recs max).
// layer 1 epilogue: h2 = relu(agg + b1) @ W2 (fp16 out)
__global__ __launch_bounds__(AGG_T) void agg_mid_kernel(const __half* __restrict__ h,
                                                        const int* __restrict__ cnt_pad,
                                                        const int* __restrict__ n_of,
                                                        const int4* __restrict__ ofr,
                                                        const int2* __restrict__ recs,
                                                        const float* __restrict__ b1,
                                                        const float* __restrict__ W2,
                                                        __half* __restrict__ h2) {
    __shared__ int2 srt[CAPB];           // 36 KB
    __shared__ int cnt[BKT_NODES];
    __shared__ int offs[BKT_NODES + 1];
    __shared__ int curs[BKT_NODES];
    __shared__ float wm[HID * HID];
    __shared__ float bs[HID];
    int t = threadIdx.x, bkt = blockIdx.x;
    if (t < HID * HID) wm[t] = W2[t];
    if (t < HID) bs[t] = b1[t];
    if (t < BKT_NODES) cnt[t] = 0;
    __syncthreads();

    int n = cnt_pad[bkt * 16]; if (n > CAPB) n = CAPB;
    const int2* brecs = recs + (size_t)bkt * CAPB;
    int lane = t & 15, grp = t >> 4;

    for (int i = t; i < n; i += AGG_T)
        atomicAdd(&cnt[((unsigned)brecs[i].x) >> 18], 1);
    __syncthreads();
    if (t == 0) {
        int run = 0;
        for (int k = 0; k < BKT_NODES; k++) { offs[k] = run; run += cnt[k]; }
        offs[BKT_NODES] = run;
    }
    __syncthreads();
    if (t < BKT_NODES) curs[t] = offs[t];
    __syncthreads();
    for (int i = t; i < n; i += AGG_T) {
        int2 r = brecs[i];
        srt[atomicAdd(&curs[((unsigned)r.x) >> 18], 1)] = r;
    }
    __syncthreads();

    float acc[NPASS];
#pragma unroll
    for (int i = 0; i < NPASS; i++) acc[i] = 0.f;

#pragma unroll
    for (int it = 0; it < NPASS; it++) {
        int ld = it * NGRP + grp;
        int pb = offs[ld], pe = offs[ld + 1];
        float a = 0.f;
        int p = pb;
        for (; p + 8 <= pe; p += 8) {
            float v[8], w[8];
#pragma unroll
            for (int u = 0; u < 8; u++) {
                int2 r = srt[p + u];
                w[u] = __int_as_float(r.y);
                v[u] = __half2float(h[(size_t)(r.x & 0x3FFFF) * HID + lane]);
            }
#pragma unroll
            for (int u = 0; u < 8; u++) a += v[u] * w[u];
        }
        for (; p < pe; ++p) {
            int2 r = srt[p];
            a += __half2float(h[(size_t)(r.x & 0x3FFFF) * HID + lane]) *
                 __int_as_float(r.y);
        }
        acc[it] += a;
    }

    // overflow records (normally zero)
    int nof = *n_of; if (nof > OF_CAP) nof = OF_CAP;
    for (int i = 0; i < nof; i++) {
        int4 r = ofr[i];
        if ((r.y >> SHIFT) == bkt) {
            int ld = r.y & (BKT_NODES - 1);
#pragma unroll
            for (int it = 0; it < NPASS; it++)
                if (it * NGRP + grp == ld)
                    acc[it] += __half2float(h[(size_t)r.x * HID + lane]) *
                               __int_as_float(r.z);
        }
    }

    // epilogue: relu(acc + b1) @ W2 via intra-wave shuffle
    int gbase = (t & 63) & ~15;
#pragma unroll
    for (int it = 0; it < NPASS; it++) {
        int node = bkt * BKT_NODES + it * NGRP + grp;
        float hv = fmaxf(acc[it] + bs[lane], 0.f);
        float o = 0.f;
#pragma unroll
        for (int k = 0; k < HID; k++)
            o += __shfl(hv, gbase + k, 64) * wm[k * HID + lane];
        if (node < N_NODES)
            h2[(size_t)node * HID + lane] = __float2half(o);
    }
}

// layer 2 epilogue: out = relu(agg + b2) @ Wd + bd (fp32 out)
__global__ __launch_bounds__(AGG_T) void agg_final_kernel(const __half* __restrict__ h2,
                                                          const int* __restrict__ cnt_pad,
                                                          const int* __restrict__ n_of,
                                                          const int4* __restrict__ ofr,
                                                          const int2* __restrict__ recs,
                                                          const float* __restrict__ b2,
                                                          const float* __restrict__ Wd,
                                                          const float* __restrict__ bd,
                                                          float* __restrict__ out) {
    __shared__ int2 srt[CAPB];
    __shared__ int cnt[BKT_NODES];
    __shared__ int offs[BKT_NODES + 1];
    __shared__ int curs[BKT_NODES];
    __shared__ float wd[HID];
    __shared__ float bs[HID];
    __shared__ float bdv;
    int t = threadIdx.x, bkt = blockIdx.x;
    if (t < HID) { wd[t] = Wd[t]; bs[t] = b2[t]; }
    if (t == 0) bdv = bd[0];
    if (t < BKT_NODES) cnt[t] = 0;
    __syncthreads();

    int n = cnt_pad[bkt * 16]; if (n > CAPB) n = CAPB;
    const int2* brecs = recs + (size_t)bkt * CAPB;
    int lane = t & 15, grp = t >> 4;

    for (int i = t; i < n; i += AGG_T)
        atomicAdd(&cnt[((unsigned)brecs[i].x) >> 18], 1);
    __syncthreads();
    if (t == 0) {
        int run = 0;
        for (int k = 0; k < BKT_NODES; k++) { offs[k] = run; run += cnt[k]; }
        offs[BKT_NODES] = run;
    }
    __syncthreads();
    if (t < BKT_NODES) curs[t] = offs[t];
    __syncthreads();
    for (int i = t; i < n; i += AGG_T) {
        int2 r = brecs[i];
        srt[atomicAdd(&curs[((unsigned)r.x) >> 18], 1)] = r;
    }
    __syncthreads();

    float acc[NPASS];
#pragma unroll
    for (int i = 0; i < NPASS; i++) acc[i] = 0.f;

#pragma unroll
    for (int it = 0; it < NPASS; it++) {
        int ld = it * NGRP + grp;
        int pb = offs[ld], pe = offs[ld + 1];
        float a = 0.f;
        int p = pb;
        for (; p + 8 <= pe; p += 8) {
            float v[8], w[8];
#pragma unroll
            for (int u = 0; u < 8; u++) {
                int2 r = srt[p + u];
                w[u] = __int_as_float(r.y);
                v[u] = __half2float(h2[(size_t)(r.x & 0x3FFFF) * HID + lane]);
            }
#pragma unroll
            for (int u = 0; u < 8; u++) a += v[u] * w[u];
        }
        for (; p < pe; ++p) {
            int2 r = srt[p];
            a += __half2float(h2[(size_t)(r.x & 0x3FFFF) * HID + lane]) *
                 __int_as_float(r.y);
        }
        acc[it] += a;
    }

    int nof = *n_of; if (nof > OF_CAP) nof = OF_CAP;
    for (int i = 0; i < nof; i++) {
        int4 r = ofr[i];
        if ((r.y >> SHIFT) == bkt) {
            int ld = r.y & (BKT_NODES - 1);
#pragma unroll
            for (int it = 0; it < NPASS; it++)
                if (it * NGRP + grp == ld)
                    acc[it] += __half2float(h2[(size_t)r.x * HID + lane]) *
                               __int_as_float(r.z);
        }
    }

#pragma unroll
    for (int it = 0; it < NPASS; it++) {
        int node = bkt * BKT_NODES + it * NGRP + grp;
        float v = fmaxf(acc[it] + bs[lane], 0.f) * wd[lane];
#pragma unroll
        for (int o = 8; o; o >>= 1) v += __shfl_xor(v, o, 64);
        if (lane == 0 && node < N_NODES) out[node] = v + bdv;
    }
}

// =================== Fallback path (R1, fp32): atomic scatter ===============
__global__ __launch_bounds__(256) void gemm1f_kernel(const float* __restrict__ x,
                                                     const float* __restrict__ W1,
                                                     float* __restrict__ h) {
    __shared__ float w[F_IN * HID];
    int tid = threadIdx.x;
    for (int i = tid; i < F_IN * HID; i += 256) w[i] = W1[i];
    __syncthreads();
    int row = blockIdx.x * 256 + tid;
    if (row >= N_NODES) return;
    float acc[HID];
#pragma unroll
    for (int j = 0; j < HID; j++) acc[j] = 0.f;
    const float4* xr = reinterpret_cast<const float4*>(x + (size_t)row * F_IN);
#pragma unroll 4
    for (int k4 = 0; k4 < F_IN / 4; k4++) {
        float4 xv = xr[k4];
        const float* wr = &w[k4 * 4 * HID];
#pragma unroll
        for (int j = 0; j < HID; j++) acc[j] += xv.x * wr[j];
#pragma unroll
        for (int j = 0; j < HID; j++) acc[j] += xv.y * wr[HID + j];
#pragma unroll
        for (int j = 0; j < HID; j++) acc[j] += xv.z * wr[2 * HID + j];
#pragma unroll
        for (int j = 0; j < HID; j++) acc[j] += xv.w * wr[3 * HID + j];
    }
    float4* hr = reinterpret_cast<float4*>(h + (size_t)row * HID);
#pragma unroll
    for (int q = 0; q < HID / 4; q++)
        hr[q] = make_float4(acc[4 * q], acc[4 * q + 1], acc[4 * q + 2], acc[4 * q + 3]);
}

__global__ __launch_bounds__(256) void scatter_kernel(const float* __restrict__ h,
                                                      const int* __restrict__ src,
                                                      const int* __restrict__ dst,
                                                      const float* __restrict__ ew,
                                                      float* __restrict__ agg,
                                                      int n_edges) {
    long long idx = (long long)blockIdx.x * 256 + threadIdx.x;
    long long total = (long long)n_edges * HID;
    if (idx >= total) return;
    int e = (int)(idx >> 4);
    int j = (int)(idx & (HID - 1));
    float val = h[(size_t)src[e] * HID + j] * ew[e];
    atomicAdd(&agg[(size_t)dst[e] * HID + j], val);
}

__global__ __launch_bounds__(256) void gemm2_kernel(const float* __restrict__ agg,
                                                    const float* __restrict__ b1,
                                                    const float* __restrict__ W2,
                                                    float* __restrict__ h2) {
    __shared__ float w[HID * HID];
    __shared__ float bias[HID];
    int tid = threadIdx.x;
    if (tid < HID * HID) w[tid] = W2[tid];
    if (tid < HID) bias[tid] = b1[tid];
    __syncthreads();
    int row = blockIdx.x * 256 + tid;
    if (row >= N_NODES) return;
    float hv[HID];
    const float4* ar = reinterpret_cast<const float4*>(agg + (size_t)row * HID);
#pragma unroll
    for (int q = 0; q < 4; q++) {
        float4 v = ar[q];
        hv[4 * q + 0] = fmaxf(v.x + bias[4 * q + 0], 0.f);
        hv[4 * q + 1] = fmaxf(v.y + bias[4 * q + 1], 0.f);
        hv[4 * q + 2] = fmaxf(v.z + bias[4 * q + 2], 0.f);
        hv[4 * q + 3] = fmaxf(v.w + bias[4 * q + 3], 0.f);
    }
    float acc[HID];
#pragma unroll
    for (int j = 0; j < HID; j++) acc[j] = 0.f;
#pragma unroll
    for (int k = 0; k < HID; k++) {
        float hk = hv[k];
#pragma unroll
        for (int j = 0; j < HID; j++) acc[j] += hk * w[k * HID + j];
    }
    float4* hr = reinterpret_cast<float4*>(h2 + (size_t)row * HID);
#pragma unroll
    for (int q = 0; q < 4; q++)
        hr[q] = make_float4(acc[4 * q], acc[4 * q + 1], acc[4 * q + 2], acc[4 * q + 3]);
}

__global__ __launch_bounds__(256) void final_kernel(const float* __restrict__ agg,
                                                    const float* __restrict__ b2,
                                                    const float* __restrict__ Wd,
                                                    const float* __restrict__ bd,
                                                    float* __restrict__ out) {
    __shared__ float wd[HID];
    __shared__ float bias[HID];
    __shared__ float bdv;
    int tid = threadIdx.x;
    if (tid < HID) { wd[tid] = Wd[tid]; bias[tid] = b2[tid]; }
    if (tid == 0) bdv = bd[0];
    __syncthreads();
    int row = blockIdx.x * 256 + tid;
    if (row >= N_NODES) return;
    const float4* ar = reinterpret_cast<const float4*>(agg + (size_t)row * HID);
    float acc = bdv;
#pragma unroll
    for (int q = 0; q < 4; q++) {
        float4 v = ar[q];
        acc += fmaxf(v.x + bias[4 * q + 0], 0.f) * wd[4 * q + 0];
        acc += fmaxf(v.y + bias[4 * q + 1], 0.f) * wd[4 * q + 1];
        acc += fmaxf(v.z + bias[4 * q + 2], 0.f) * wd[4 * q + 2];
        acc += fmaxf(v.w + bias[4 * q + 3], 0.f) * wd[4 * q + 3];
    }
    out[row] = acc;
}

extern "C" void kernel_launch(void* const* d_in, const int* in_sizes, int n_in,
                              void* d_out, int out_size, void* d_ws, size_t ws_size,
                              hipStream_t stream) {
    const float* x    = (const float*)d_in[0];
    const int*   esrc = (const int*)d_in[1];
    const int*   edst = (const int*)d_in[2];
    const float* ew   = (const float*)d_in[3];
    const float* W1   = (const float*)d_in[4];
    const float* b1   = (const float*)d_in[5];
    const float* W2   = (const float*)d_in[6];
    const float* b2   = (const float*)d_in[7];
    const float* Wd   = (const float*)d_in[8];
    const float* bd   = (const float*)d_in[9];
    float* out = (float*)d_out;

    int n_edges = in_sizes[1];
    int num_node_blocks = (N_NODES + 255) / 256;

    // ---- workspace layout (fast path) ----
    size_t hbuf   = (size_t)N_NODES * HID * sizeof(__half);     // 6.4 MB x2
    size_t cnt_b  = (size_t)NB * 64;                            // 100 KB padded
    size_t nof_b  = 64;
    size_t ofr_b  = (size_t)OF_CAP * 16;                        // 1 MB
    size_t recs_b = (size_t)NB * CAPB * 8;                      // 57.6 MB

    size_t needed = 2 * hbuf + cnt_b + nof_b + ofr_b + recs_b;

    if (ws_size >= needed && n_edges > 0) {
        char* p = (char*)d_ws;
        __half* hA   = (__half*)p;  p += hbuf;
        __half* hB   = (__half*)p;  p += hbuf;
        int* cnt_pad = (int*)p;     p += cnt_b;
        int* n_of    = (int*)p;     p += nof_b;
        int4* ofr    = (int4*)p;    p += ofr_b;
        int2* recs   = (int2*)p;

        gemm1_kernel<<<num_node_blocks, 256, 0, stream>>>(x, W1, hA);

        hipMemsetAsync(cnt_pad, 0, cnt_b + nof_b, stream);  // cursors + n_of
        partition_kernel<<<PART_BLOCKS, 256, 0, stream>>>(esrc, edst, ew, cnt_pad,
                                                          n_of, ofr, recs, n_edges);

        agg_mid_kernel<<<NB, AGG_T, 0, stream>>>(hA, cnt_pad, n_of, ofr, recs,
                                                 b1, W2, hB);
        agg_final_kernel<<<NB, AGG_T, 0, stream>>>(hB, cnt_pad, n_of, ofr, recs,
                                                   b2, Wd, bd, out);
    } else {
        // Fallback: R1 atomic path (fp32, needs only 2 node buffers)
        size_t node_buf = (size_t)N_NODES * HID * sizeof(float);
        float* bufA = (float*)d_ws;
        float* bufB = (float*)((char*)d_ws + node_buf);
        long long scatter_work = (long long)n_edges * HID;
        int scatter_blocks = (int)((scatter_work + 255) / 256);
        gemm1f_kernel<<<num_node_blocks, 256, 0, stream>>>(x, W1, bufA);
        hipMemsetAsync(bufB, 0, node_buf, stream);
        scatter_kernel<<<scatter_blocks, 256, 0, stream>>>(bufA, esrc, edst, ew, bufB, n_edges);
        gemm2_kernel<<<num_node_blocks, 256, 0, stream>>>(bufB, b1, W2, bufA);
        hipMemsetAsync(bufB, 0, node_buf, stream);
        scatter_kernel<<<scatter_blocks, 256, 0, stream>>>(bufA, esrc, edst, ew, bufB, n_edges);
        final_kernel<<<num_node_blocks, 256, 0, stream>>>(bufB, b2, Wd, bd, out);
    }
}

// Round 15
// 476.750 us; speedup vs baseline: 1.0611x; 1.0611x over previous
//
#include <hip/hip_runtime.h>
#include <hip/hip_fp16.h>

#define N_NODES 200000
#define F_IN 128
#define HID 16
#define SHIFT 7
#define BKT_NODES 128              // 1 << SHIFT
#define NB 1563                    // ceil(N_NODES / 128)
#define NXCD 8
#define CAPS 768                   // per-(bucket,xcd) segment capacity (mean 512)
#define SEG_TOT (NXCD * CAPS)      // 6144 -> 48 KB LDS sort buffer
#define OF_CAP 65536               // overflow list capacity
#define PART_BLOCKS 2048
#define AGG_T 512
#define NGRP (AGG_T / 16)          // 32 node-groups per pass
#define NPASS (BKT_NODES / NGRP)   // 4

// ---- non-temporal load helpers (pure streaming reads) ----------------------
__device__ __forceinline__ int ldnt_i(const int* p) {
    return __builtin_nontemporal_load(p);
}
__device__ __forceinline__ float ldnt_f(const float* p) {
    return __builtin_nontemporal_load(p);
}

// ---------------- Stage 1: h = x @ W1 -> fp16 [N,16] -----------------------
__global__ __launch_bounds__(256) void gemm1_kernel(const float* __restrict__ x,
                                                    const float* __restrict__ W1,
                                                    __half* __restrict__ h) {
    __shared__ float w[F_IN * HID];  // 8 KB
    int tid = threadIdx.x;
    for (int i = tid; i < F_IN * HID; i += 256) w[i] = W1[i];
    __syncthreads();

    int row = blockIdx.x * 256 + tid;
    if (row >= N_NODES) return;

    float acc[HID];
#pragma unroll
    for (int j = 0; j < HID; j++) acc[j] = 0.f;

    const float4* xr = reinterpret_cast<const float4*>(x + (size_t)row * F_IN);
#pragma unroll 4
    for (int k4 = 0; k4 < F_IN / 4; k4++) {
        float4 xv = xr[k4];
        const float* wr = &w[k4 * 4 * HID];
#pragma unroll
        for (int j = 0; j < HID; j++) acc[j] += xv.x * wr[j];
#pragma unroll
        for (int j = 0; j < HID; j++) acc[j] += xv.y * wr[HID + j];
#pragma unroll
        for (int j = 0; j < HID; j++) acc[j] += xv.z * wr[2 * HID + j];
#pragma unroll
        for (int j = 0; j < HID; j++) acc[j] += xv.w * wr[3 * HID + j];
    }

    union { __half hh[16]; uint4 u[2]; } pk;
#pragma unroll
    for (int j = 0; j < HID; j++) pk.hh[j] = __float2half(acc[j]);
    uint4* hr = reinterpret_cast<uint4*>(h + (size_t)row * HID);
    hr[0] = pk.u[0];
    hr[1] = pk.u[1];
}

// ---------------- Partition: per-XCD bump allocation ------------------------
// Cursor per (bucket, xcd). All writers of a segment share one XCD's L2:
// no cross-XCD line splitting (R14's bug), and only ~1563 open lines per L2
// (vs R6's 50k chip-wide). record: {src | local_dst<<18, weight_bits}
__global__ __launch_bounds__(256) void partition_kernel(const int* __restrict__ src,
                                                        const int* __restrict__ dst,
                                                        const float* __restrict__ ew,
                                                        int* __restrict__ cnt_pad,
                                                        int* __restrict__ n_of,
                                                        int4* __restrict__ ofr,
                                                        int2* __restrict__ recs,
                                                        int n_edges) {
    unsigned xcc;
    asm("s_getreg_b32 %0, hwreg(HW_REG_XCC_ID)" : "=s"(xcc));
    int k = (int)(xcc & (NXCD - 1));
    int stride = gridDim.x * 256;
    for (int e = blockIdx.x * 256 + threadIdx.x; e < n_edges; e += stride) {
        int d = ldnt_i(&dst[e]);
        int s = ldnt_i(&src[e]);
        float w = ldnt_f(&ew[e]);
        int seg = (d >> SHIFT) * NXCD + k;
        int pos = atomicAdd(&cnt_pad[seg * 16], 1);  // one counter per 64B line
        if (pos < CAPS) {
            recs[(size_t)seg * CAPS + pos] =
                make_int2(s | ((d & (BKT_NODES - 1)) << 18), __float_as_int(w));
        } else {
            int of = atomicAdd(n_of, 1);
            if (of < OF_CAP) ofr[of] = make_int4(s, d, __float_as_int(w), 0);
        }
    }
}

// ---------------- Aggregation: in-LDS counting sort + register acc ----------
// One block per bucket; reads the bucket's 8 per-XCD segments, sorts by local
// dst into one LDS buffer, then 16 lanes/node accumulate (R6-verified engine).
// layer 1 epilogue: h2 = relu(agg + b1) @ W2 (fp16 out)
__global__ __launch_bounds__(AGG_T) void agg_mid_kernel(const __half* __restrict__ h,
                                                        const int* __restrict__ cnt_pad,
                                                        const int* __restrict__ n_of,
                                                        const int4* __restrict__ ofr,
                                                        const int2* __restrict__ recs,
                                                        const float* __restrict__ b1,
                                                        const float* __restrict__ W2,
                                                        __half* __restrict__ h2) {
    __shared__ int2 srt[SEG_TOT];        // 48 KB
    __shared__ int scnt[NXCD];
    __shared__ int cnt[BKT_NODES];
    __shared__ int offs[BKT_NODES + 1];
    __shared__ int curs[BKT_NODES];
    __shared__ float wm[HID * HID];
    __shared__ float bs[HID];
    int t = threadIdx.x, bkt = blockIdx.x;
    if (t < HID * HID) wm[t] = W2[t];
    if (t < HID) bs[t] = b1[t];
    if (t < BKT_NODES) cnt[t] = 0;
    if (t < NXCD) {
        int c = cnt_pad[(bkt * NXCD + t) * 16];
        scnt[t] = (c > CAPS) ? CAPS : c;
    }
    __syncthreads();

    int lane = t & 15, grp = t >> 4;

    for (int k = 0; k < NXCD; k++) {
        const int2* brecs = recs + (size_t)(bkt * NXCD + k) * CAPS;
        int nk = scnt[k];
        for (int i = t; i < nk; i += AGG_T)
            atomicAdd(&cnt[((unsigned)brecs[i].x) >> 18], 1);
    }
    __syncthreads();
    if (t == 0) {
        int run = 0;
        for (int q = 0; q < BKT_NODES; q++) { offs[q] = run; run += cnt[q]; }
        offs[BKT_NODES] = run;
    }
    __syncthreads();
    if (t < BKT_NODES) curs[t] = offs[t];
    __syncthreads();
    for (int k = 0; k < NXCD; k++) {
        const int2* brecs = recs + (size_t)(bkt * NXCD + k) * CAPS;
        int nk = scnt[k];
        for (int i = t; i < nk; i += AGG_T) {
            int2 r = brecs[i];
            srt[atomicAdd(&curs[((unsigned)r.x) >> 18], 1)] = r;
        }
    }
    __syncthreads();

    float acc[NPASS];
#pragma unroll
    for (int i = 0; i < NPASS; i++) acc[i] = 0.f;

#pragma unroll
    for (int it = 0; it < NPASS; it++) {
        int ld = it * NGRP + grp;
        int pb = offs[ld], pe = offs[ld + 1];
        float a = 0.f;
        int p = pb;
        for (; p + 8 <= pe; p += 8) {
            float v[8], w[8];
#pragma unroll
            for (int u = 0; u < 8; u++) {
                int2 r = srt[p + u];
                w[u] = __int_as_float(r.y);
                v[u] = __half2float(h[(size_t)(r.x & 0x3FFFF) * HID + lane]);
            }
#pragma unroll
            for (int u = 0; u < 8; u++) a += v[u] * w[u];
        }
        for (; p < pe; ++p) {
            int2 r = srt[p];
            a += __half2float(h[(size_t)(r.x & 0x3FFFF) * HID + lane]) *
                 __int_as_float(r.y);
        }
        acc[it] += a;
    }

    // overflow records (normally zero)
    int nof = *n_of; if (nof > OF_CAP) nof = OF_CAP;
    for (int i = 0; i < nof; i++) {
        int4 r = ofr[i];
        if ((r.y >> SHIFT) == bkt) {
            int ld = r.y & (BKT_NODES - 1);
#pragma unroll
            for (int it = 0; it < NPASS; it++)
                if (it * NGRP + grp == ld)
                    acc[it] += __half2float(h[(size_t)r.x * HID + lane]) *
                               __int_as_float(r.z);
        }
    }

    // epilogue: relu(acc + b1) @ W2 via intra-wave shuffle
    int gbase = (t & 63) & ~15;
#pragma unroll
    for (int it = 0; it < NPASS; it++) {
        int node = bkt * BKT_NODES + it * NGRP + grp;
        float hv = fmaxf(acc[it] + bs[lane], 0.f);
        float o = 0.f;
#pragma unroll
        for (int q = 0; q < HID; q++)
            o += __shfl(hv, gbase + q, 64) * wm[q * HID + lane];
        if (node < N_NODES)
            h2[(size_t)node * HID + lane] = __float2half(o);
    }
}

// layer 2 epilogue: out = relu(agg + b2) @ Wd + bd (fp32 out)
__global__ __launch_bounds__(AGG_T) void agg_final_kernel(const __half* __restrict__ h2,
                                                          const int* __restrict__ cnt_pad,
                                                          const int* __restrict__ n_of,
                                                          const int4* __restrict__ ofr,
                                                          const int2* __restrict__ recs,
                                                          const float* __restrict__ b2,
                                                          const float* __restrict__ Wd,
                                                          const float* __restrict__ bd,
                                                          float* __restrict__ out) {
    __shared__ int2 srt[SEG_TOT];
    __shared__ int scnt[NXCD];
    __shared__ int cnt[BKT_NODES];
    __shared__ int offs[BKT_NODES + 1];
    __shared__ int curs[BKT_NODES];
    __shared__ float wd[HID];
    __shared__ float bs[HID];
    __shared__ float bdv;
    int t = threadIdx.x, bkt = blockIdx.x;
    if (t < HID) { wd[t] = Wd[t]; bs[t] = b2[t]; }
    if (t == 0) bdv = bd[0];
    if (t < BKT_NODES) cnt[t] = 0;
    if (t < NXCD) {
        int c = cnt_pad[(bkt * NXCD + t) * 16];
        scnt[t] = (c > CAPS) ? CAPS : c;
    }
    __syncthreads();

    int lane = t & 15, grp = t >> 4;

    for (int k = 0; k < NXCD; k++) {
        const int2* brecs = recs + (size_t)(bkt * NXCD + k) * CAPS;
        int nk = scnt[k];
        for (int i = t; i < nk; i += AGG_T)
            atomicAdd(&cnt[((unsigned)brecs[i].x) >> 18], 1);
    }
    __syncthreads();
    if (t == 0) {
        int run = 0;
        for (int q = 0; q < BKT_NODES; q++) { offs[q] = run; run += cnt[q]; }
        offs[BKT_NODES] = run;
    }
    __syncthreads();
    if (t < BKT_NODES) curs[t] = offs[t];
    __syncthreads();
    for (int k = 0; k < NXCD; k++) {
        const int2* brecs = recs + (size_t)(bkt * NXCD + k) * CAPS;
        int nk = scnt[k];
        for (int i = t; i < nk; i += AGG_T) {
            int2 r = brecs[i];
            srt[atomicAdd(&curs[((unsigned)r.x) >> 18], 1)] = r;
        }
    }
    __syncthreads();

    float acc[NPASS];
#pragma unroll
    for (int i = 0; i < NPASS; i++) acc[i] = 0.f;

#pragma unroll
    for (int it = 0; it < NPASS; it++) {
        int ld = it * NGRP + grp;
        int pb = offs[ld], pe = offs[ld + 1];
        float a = 0.f;
        int p = pb;
        for (; p + 8 <= pe; p += 8) {
            float v[8], w[8];
#pragma unroll
            for (int u = 0; u < 8; u++) {
                int2 r = srt[p + u];
                w[u] = __int_as_float(r.y);
                v[u] = __half2float(h2[(size_t)(r.x & 0x3FFFF) * HID + lane]);
            }
#pragma unroll
            for (int u = 0; u < 8; u++) a += v[u] * w[u];
        }
        for (; p < pe; ++p) {
            int2 r = srt[p];
            a += __half2float(h2[(size_t)(r.x & 0x3FFFF) * HID + lane]) *
                 __int_as_float(r.y);
        }
        acc[it] += a;
    }

    int nof = *n_of; if (nof > OF_CAP) nof = OF_CAP;
    for (int i = 0; i < nof; i++) {
        int4 r = ofr[i];
        if ((r.y >> SHIFT) == bkt) {
            int ld = r.y & (BKT_NODES - 1);
#pragma unroll
            for (int it = 0; it < NPASS; it++)
                if (it * NGRP + grp == ld)
                    acc[it] += __half2float(h2[(size_t)r.x * HID + lane]) *
                               __int_as_float(r.z);
        }
    }

#pragma unroll
    for (int it = 0; it < NPASS; it++) {
        int node = bkt * BKT_NODES + it * NGRP + grp;
        float v = fmaxf(acc[it] + bs[lane], 0.f) * wd[lane];
#pragma unroll
        for (int o = 8; o; o >>= 1) v += __shfl_xor(v, o, 64);
        if (lane == 0 && node < N_NODES) out[node] = v + bdv;
    }
}

// =================== Fallback path (R1, fp32): atomic scatter ===============
__global__ __launch_bounds__(256) void gemm1f_kernel(const float* __restrict__ x,
                                                     const float* __restrict__ W1,
                                                     float* __restrict__ h) {
    __shared__ float w[F_IN * HID];
    int tid = threadIdx.x;
    for (int i = tid; i < F_IN * HID; i += 256) w[i] = W1[i];
    __syncthreads();
    int row = blockIdx.x * 256 + tid;
    if (row >= N_NODES) return;
    float acc[HID];
#pragma unroll
    for (int j = 0; j < HID; j++) acc[j] = 0.f;
    const float4* xr = reinterpret_cast<const float4*>(x + (size_t)row * F_IN);
#pragma unroll 4
    for (int k4 = 0; k4 < F_IN / 4; k4++) {
        float4 xv = xr[k4];
        const float* wr = &w[k4 * 4 * HID];
#pragma unroll
        for (int j = 0; j < HID; j++) acc[j] += xv.x * wr[j];
#pragma unroll
        for (int j = 0; j < HID; j++) acc[j] += xv.y * wr[HID + j];
#pragma unroll
        for (int j = 0; j < HID; j++) acc[j] += xv.z * wr[2 * HID + j];
#pragma unroll
        for (int j = 0; j < HID; j++) acc[j] += xv.w * wr[3 * HID + j];
    }
    float4* hr = reinterpret_cast<float4*>(h + (size_t)row * HID);
#pragma unroll
    for (int q = 0; q < HID / 4; q++)
        hr[q] = make_float4(acc[4 * q], acc[4 * q + 1], acc[4 * q + 2], acc[4 * q + 3]);
}

__global__ __launch_bounds__(256) void scatter_kernel(const float* __restrict__ h,
                                                      const int* __restrict__ src,
                                                      const int* __restrict__ dst,
                                                      const float* __restrict__ ew,
                                                      float* __restrict__ agg,
                                                      int n_edges) {
    long long idx = (long long)blockIdx.x * 256 + threadIdx.x;
    long long total = (long long)n_edges * HID;
    if (idx >= total) return;
    int e = (int)(idx >> 4);
    int j = (int)(idx & (HID - 1));
    float val = h[(size_t)src[e] * HID + j] * ew[e];
    atomicAdd(&agg[(size_t)dst[e] * HID + j], val);
}

__global__ __launch_bounds__(256) void gemm2_kernel(const float* __restrict__ agg,
                                                    const float* __restrict__ b1,
                                                    const float* __restrict__ W2,
                                                    float* __restrict__ h2) {
    __shared__ float w[HID * HID];
    __shared__ float bias[HID];
    int tid = threadIdx.x;
    if (tid < HID * HID) w[tid] = W2[tid];
    if (tid < HID) bias[tid] = b1[tid];
    __syncthreads();
    int row = blockIdx.x * 256 + tid;
    if (row >= N_NODES) return;
    float hv[HID];
    const float4* ar = reinterpret_cast<const float4*>(agg + (size_t)row * HID);
#pragma unroll
    for (int q = 0; q < 4; q++) {
        float4 v = ar[q];
        hv[4 * q + 0] = fmaxf(v.x + bias[4 * q + 0], 0.f);
        hv[4 * q + 1] = fmaxf(v.y + bias[4 * q + 1], 0.f);
        hv[4 * q + 2] = fmaxf(v.z + bias[4 * q + 2], 0.f);
        hv[4 * q + 3] = fmaxf(v.w + bias[4 * q + 3], 0.f);
    }
    float acc[HID];
#pragma unroll
    for (int j = 0; j < HID; j++) acc[j] = 0.f;
#pragma unroll
    for (int k = 0; k < HID; k++) {
        float hk = hv[k];
#pragma unroll
        for (int j = 0; j < HID; j++) acc[j] += hk * w[k * HID + j];
    }
    float4* hr = reinterpret_cast<float4*>(h2 + (size_t)row * HID);
#pragma unroll
    for (int q = 0; q < 4; q++)
        hr[q] = make_float4(acc[4 * q], acc[4 * q + 1], acc[4 * q + 2], acc[4 * q + 3]);
}

__global__ __launch_bounds__(256) void final_kernel(const float* __restrict__ agg,
                                                    const float* __restrict__ b2,
                                                    const float* __restrict__ Wd,
                                                    const float* __restrict__ bd,
                                                    float* __restrict__ out) {
    __shared__ float wd[HID];
    __shared__ float bias[HID];
    __shared__ float bdv;
    int tid = threadIdx.x;
    if (tid < HID) { wd[tid] = Wd[tid]; bias[tid] = b2[tid]; }
    if (tid == 0) bdv = bd[0];
    __syncthreads();
    int row = blockIdx.x * 256 + tid;
    if (row >= N_NODES) return;
    const float4* ar = reinterpret_cast<const float4*>(agg + (size_t)row * HID);
    float acc = bdv;
#pragma unroll
    for (int q = 0; q < 4; q++) {
        float4 v = ar[q];
        acc += fmaxf(v.x + bias[4 * q + 0], 0.f) * wd[4 * q + 0];
        acc += fmaxf(v.y + bias[4 * q + 1], 0.f) * wd[4 * q + 1];
        acc += fmaxf(v.z + bias[4 * q + 2], 0.f) * wd[4 * q + 2];
        acc += fmaxf(v.w + bias[4 * q + 3], 0.f) * wd[4 * q + 3];
    }
    out[row] = acc;
}

extern "C" void kernel_launch(void* const* d_in, const int* in_sizes, int n_in,
                              void* d_out, int out_size, void* d_ws, size_t ws_size,
                              hipStream_t stream) {
    const float* x    = (const float*)d_in[0];
    const int*   esrc = (const int*)d_in[1];
    const int*   edst = (const int*)d_in[2];
    const float* ew   = (const float*)d_in[3];
    const float* W1   = (const float*)d_in[4];
    const float* b1   = (const float*)d_in[5];
    const float* W2   = (const float*)d_in[6];
    const float* b2   = (const float*)d_in[7];
    const float* Wd   = (const float*)d_in[8];
    const float* bd   = (const float*)d_in[9];
    float* out = (float*)d_out;

    int n_edges = in_sizes[1];
    int num_node_blocks = (N_NODES + 255) / 256;

    // ---- workspace layout (fast path) ----
    size_t hbuf   = (size_t)N_NODES * HID * sizeof(__half);     // 6.4 MB x2
    size_t cnt_b  = (size_t)NB * NXCD * 64;                     // 0.8 MB padded
    size_t nof_b  = 64;
    size_t ofr_b  = (size_t)OF_CAP * 16;                        // 1 MB
    size_t recs_b = (size_t)NB * NXCD * CAPS * 8;               // 76.8 MB

    size_t needed = 2 * hbuf + cnt_b + nof_b + ofr_b + recs_b;

    if (ws_size >= needed && n_edges > 0) {
        char* p = (char*)d_ws;
        __half* hA   = (__half*)p;  p += hbuf;
        __half* hB   = (__half*)p;  p += hbuf;
        int* cnt_pad = (int*)p;     p += cnt_b;
        int* n_of    = (int*)p;     p += nof_b;
        int4* ofr    = (int4*)p;    p += ofr_b;
        int2* recs   = (int2*)p;

        gemm1_kernel<<<num_node_blocks, 256, 0, stream>>>(x, W1, hA);

        hipMemsetAsync(cnt_pad, 0, cnt_b + nof_b, stream);  // cursors + n_of
        partition_kernel<<<PART_BLOCKS, 256, 0, stream>>>(esrc, edst, ew, cnt_pad,
                                                          n_of, ofr, recs, n_edges);

        agg_mid_kernel<<<NB, AGG_T, 0, stream>>>(hA, cnt_pad, n_of, ofr, recs,
                                                 b1, W2, hB);
        agg_final_kernel<<<NB, AGG_T, 0, stream>>>(hB, cnt_pad, n_of, ofr, recs,
                                                   b2, Wd, bd, out);
    } else {
        // Fallback: R1 atomic path (fp32, needs only 2 node buffers)
        size_t node_buf = (size_t)N_NODES * HID * sizeof(float);
        float* bufA = (float*)d_ws;
        float* bufB = (float*)((char*)d_ws + node_buf);
        long long scatter_work = (long long)n_edges * HID;
        int scatter_blocks = (int)((scatter_work + 255) / 256);
        gemm1f_kernel<<<num_node_blocks, 256, 0, stream>>>(x, W1, bufA);
        hipMemsetAsync(bufB, 0, node_buf, stream);
        scatter_kernel<<<scatter_blocks, 256, 0, stream>>>(bufA, esrc, edst, ew, bufB, n_edges);
        gemm2_kernel<<<num_node_blocks, 256, 0, stream>>>(bufB, b1, W2, bufA);
        hipMemsetAsync(bufB, 0, node_buf, stream);
        scatter_kernel<<<scatter_blocks, 256, 0, stream>>>(bufA, esrc, edst, ew, bufB, n_edges);
        final_kernel<<<num_node_blocks, 256, 0, stream>>>(bufB, b2, Wd, bd, out);
    }
}

// Round 16
// 287.851 us; speedup vs baseline: 1.7575x; 1.6562x over previous
//
#include <hip/hip_runtime.h>
#include <hip/hip_fp16.h>

#define N_NODES 200000
#define F_IN 128
#define HID 16

#define SHIFT_C 12
#define CNODES 4096
#define NC 49                     // ceil(N_NODES / 4096)
#define SHIFT_F 7
#define BKT_NODES 128
#define FPC 32                    // fine per coarse
#define NF (NC * FPC)             // 1568 (only 0..1562 populated)
#define NAGG 1563                 // fine buckets covering real nodes

#define TILE 4096                 // LDS sort tile (32 KB of int2)
#define PBLK 512
#define HBLK 256                  // histboth grid

#define CAP 4608                  // agg in-LDS sort chunk
#define AGG_T 512
#define NGRP (AGG_T / 16)
#define NPASS (BKT_NODES / NGRP)  // 4

// ---- non-temporal load helpers (pure streaming reads) ----------------------
__device__ __forceinline__ int ldnt_i(const int* p) {
    return __builtin_nontemporal_load(p);
}
__device__ __forceinline__ float ldnt_f(const float* p) {
    return __builtin_nontemporal_load(p);
}

// ---------------- Stage 1: h = x @ W1 -> fp16 [N,16] -----------------------
__global__ __launch_bounds__(256) void gemm1_kernel(const float* __restrict__ x,
                                                    const float* __restrict__ W1,
                                                    __half* __restrict__ h) {
    __shared__ float w[F_IN * HID];  // 8 KB
    int tid = threadIdx.x;
    for (int i = tid; i < F_IN * HID; i += 256) w[i] = W1[i];
    __syncthreads();

    int row = blockIdx.x * 256 + tid;
    if (row >= N_NODES) return;

    float acc[HID];
#pragma unroll
    for (int j = 0; j < HID; j++) acc[j] = 0.f;

    const float4* xr = reinterpret_cast<const float4*>(x + (size_t)row * F_IN);
#pragma unroll 4
    for (int k4 = 0; k4 < F_IN / 4; k4++) {
        float4 xv = xr[k4];
        const float* wr = &w[k4 * 4 * HID];
#pragma unroll
        for (int j = 0; j < HID; j++) acc[j] += xv.x * wr[j];
#pragma unroll
        for (int j = 0; j < HID; j++) acc[j] += xv.y * wr[HID + j];
#pragma unroll
        for (int j = 0; j < HID; j++) acc[j] += xv.z * wr[2 * HID + j];
#pragma unroll
        for (int j = 0; j < HID; j++) acc[j] += xv.w * wr[3 * HID + j];
    }

    union { __half hh[16]; uint4 u[2]; } pk;
#pragma unroll
    for (int j = 0; j < HID; j++) pk.hh[j] = __float2half(acc[j]);
    uint4* hr = reinterpret_cast<uint4*>(h + (size_t)row * HID);
    hr[0] = pk.u[0];
    hr[1] = pk.u[1];
}

// ---------------- Fine histogram (single edge read) -------------------------
__global__ __launch_bounds__(PBLK) void histboth_kernel(const int* __restrict__ dst,
                                                        int* __restrict__ h2g,
                                                        int n_edges, int chunk) {
    __shared__ int hcf[NF];  // 6.3 KB
    int t = threadIdx.x, blk = blockIdx.x;
    for (int i = t; i < NF; i += PBLK) hcf[i] = 0;
    __syncthreads();
    int e0 = blk * chunk;
    int e1 = e0 + chunk; if (e1 > n_edges) e1 = n_edges;
    for (int e = e0 + t; e < e1; e += PBLK)
        atomicAdd(&hcf[ldnt_i(&dst[e]) >> SHIFT_F], 1);
    __syncthreads();
    for (int f = t; f < NF; f += PBLK)
        if (hcf[f]) atomicAdd(&h2g[f], hcf[f]);
}

// ---------------- Scan: fine bases + coarse bases + cursors -----------------
__global__ __launch_bounds__(512) void scanall_kernel(const int* __restrict__ h2g,
                                                      int* __restrict__ base2,
                                                      int* __restrict__ gcur2,
                                                      int* __restrict__ base1,
                                                      int* __restrict__ gcur1,
                                                      int n_edges) {
    __shared__ int s[512];
    __shared__ int carry;
    int t = threadIdx.x;
    if (t == 0) carry = 0;
    __syncthreads();
    for (int b0 = 0; b0 < NF; b0 += 512) {
        int v = (b0 + t < NF) ? h2g[b0 + t] : 0;
        s[t] = v; __syncthreads();
        for (int o = 1; o < 512; o <<= 1) {
            int u = (t >= o) ? s[t - o] : 0; __syncthreads();
            s[t] += u; __syncthreads();
        }
        if (b0 + t < NF) {
            int ex = carry + s[t] - v;
            base2[b0 + t] = ex;
            gcur2[b0 + t] = ex;
        }
        __syncthreads();
        if (t == 0) carry += s[511];
        __syncthreads();
    }
    if (t == 0) base2[NF] = n_edges;
    __syncthreads();
    if (t < NC) {
        base1[t] = base2[t * FPC];
        gcur1[t] = base2[t * FPC];
    }
    if (t == 0) base1[NC] = n_edges;
}

// ---------------- Pass 1: tile-sort by coarse, coalesced run writes ---------
// record: {src | ldc<<18, weight_bits}, ldc = dst & 4095
__global__ __launch_bounds__(PBLK) void pass1_kernel(const int* __restrict__ src,
                                                     const int* __restrict__ dst,
                                                     const float* __restrict__ ew,
                                                     int* __restrict__ gcur1,
                                                     int2* __restrict__ recs1,
                                                     int n_edges) {
    __shared__ int2 srt[TILE];              // 32 KB
    __shared__ unsigned char cid[TILE];     // 4 KB (coarse id per slot)
    __shared__ int cnt[NC], offs[NC], curs[NC], gpos[NC];
    int t = threadIdx.x;
    int e0 = blockIdx.x * TILE;
    int n = n_edges - e0; if (n > TILE) n = TILE;
    if (n <= 0) return;

    if (t < NC) cnt[t] = 0;
    __syncthreads();
    for (int i = t; i < n; i += PBLK)
        atomicAdd(&cnt[ldnt_i(&dst[e0 + i]) >> SHIFT_C], 1);
    __syncthreads();
    if (t == 0) {
        int run = 0;
        for (int c = 0; c < NC; c++) { offs[c] = run; run += cnt[c]; }
    }
    __syncthreads();
    if (t < NC) curs[t] = offs[t];
    __syncthreads();
    for (int i = t; i < n; i += PBLK) {
        int d = ldnt_i(&dst[e0 + i]);
        int s = ldnt_i(&src[e0 + i]);
        float w = ldnt_f(&ew[e0 + i]);
        int c = d >> SHIFT_C;
        int pos = atomicAdd(&curs[c], 1);
        srt[pos] = make_int2(s | ((d & (CNODES - 1)) << 18), __float_as_int(w));
        cid[pos] = (unsigned char)c;
    }
    __syncthreads();
    if (t < NC) gpos[t] = atomicAdd(&gcur1[t], cnt[t]);
    __syncthreads();
    // coalesced run write: consecutive i within a run -> consecutive global
    for (int i = t; i < n; i += PBLK) {
        int c = cid[i];
        recs1[gpos[c] + (i - offs[c])] = srt[i];
    }
}

// ---------------- Pass 2: tile-sort coarse segments by fine -----------------
__global__ __launch_bounds__(PBLK) void pass2_kernel(const int2* __restrict__ recs1,
                                                     const int* __restrict__ base1,
                                                     int* __restrict__ gcur2,
                                                     int2* __restrict__ recs2) {
    __shared__ int2 srt[TILE];
    __shared__ int cnt[FPC], offs[FPC], curs[FPC], gpos[FPC];
    int t = threadIdx.x;

    // map blockIdx.x -> (coarse c, tile j)
    int bid = blockIdx.x, c = -1, j = 0, acc = 0;
    for (int cc = 0; cc < NC; ++cc) {
        int sz = base1[cc + 1] - base1[cc];
        int ntl = (sz + TILE - 1) / TILE;
        if (bid < acc + ntl) { c = cc; j = bid - acc; break; }
        acc += ntl;
    }
    if (c < 0) return;
    int beg = base1[c] + j * TILE;
    int n = base1[c + 1] - beg; if (n > TILE) n = TILE;
    if (n <= 0) return;

    if (t < FPC) cnt[t] = 0;
    __syncthreads();
    for (int i = t; i < n; i += PBLK)
        atomicAdd(&cnt[(recs1[beg + i].x >> 25) & (FPC - 1)], 1);
    __syncthreads();
    if (t == 0) {
        int run = 0;
        for (int f = 0; f < FPC; f++) { offs[f] = run; run += cnt[f]; }
    }
    __syncthreads();
    if (t < FPC) curs[t] = offs[t];
    __syncthreads();
    for (int i = t; i < n; i += PBLK) {
        int2 r = recs1[beg + i];
        int f = (r.x >> 25) & (FPC - 1);
        srt[atomicAdd(&curs[f], 1)] = r;
    }
    __syncthreads();
    if (t < FPC) gpos[t] = atomicAdd(&gcur2[c * FPC + t], cnt[t]);
    __syncthreads();
    for (int i = t; i < n; i += PBLK) {
        int2 r = srt[i];
        int f = (r.x >> 25) & (FPC - 1);
        recs2[gpos[f] + (i - offs[f])] = r;
    }
}

// ---------------- Aggregation: R6 engine (bases from plain fine scan) -------
// local dst within fine bucket = (r.x >> 18) & 127
// layer 1 epilogue: h2 = relu(agg + b1) @ W2 (fp16 out)
__global__ __launch_bounds__(AGG_T) void agg_mid_kernel(const __half* __restrict__ h,
                                                        const int* __restrict__ base2,
                                                        const int2* __restrict__ recs,
                                                        const float* __restrict__ b1,
                                                        const float* __restrict__ W2,
                                                        __half* __restrict__ h2) {
    __shared__ int2 srt[CAP];            // 36 KB
    __shared__ int cnt[BKT_NODES];
    __shared__ int offs[BKT_NODES + 1];
    __shared__ int curs[BKT_NODES];
    __shared__ float wm[HID * HID];
    __shared__ float bs[HID];
    int t = threadIdx.x, bkt = blockIdx.x;
    if (t < HID * HID) wm[t] = W2[t];
    if (t < HID) bs[t] = b1[t];
    __syncthreads();

    int beg = base2[bkt];
    int end = base2[bkt + 1];
    int lane = t & 15, grp = t >> 4;

    float acc[NPASS];
#pragma unroll
    for (int i = 0; i < NPASS; i++) acc[i] = 0.f;

    for (int c0 = beg; c0 < end; c0 += CAP) {
        int n = end - c0; if (n > CAP) n = CAP;
        if (t < BKT_NODES) cnt[t] = 0;
        __syncthreads();
        for (int i = t; i < n; i += AGG_T)
            atomicAdd(&cnt[(recs[c0 + i].x >> 18) & (BKT_NODES - 1)], 1);
        __syncthreads();
        if (t == 0) {
            int run = 0;
            for (int k = 0; k < BKT_NODES; k++) { offs[k] = run; run += cnt[k]; }
            offs[BKT_NODES] = run;
        }
        __syncthreads();
        if (t < BKT_NODES) curs[t] = offs[t];
        __syncthreads();
        for (int i = t; i < n; i += AGG_T) {
            int2 r = recs[c0 + i];
            srt[atomicAdd(&curs[(r.x >> 18) & (BKT_NODES - 1)], 1)] = r;
        }
        __syncthreads();

#pragma unroll
        for (int it = 0; it < NPASS; it++) {
            int ld = it * NGRP + grp;
            int pb = offs[ld], pe = offs[ld + 1];
            float a = 0.f;
            int p = pb;
            for (; p + 8 <= pe; p += 8) {
                float v[8], w[8];
#pragma unroll
                for (int u = 0; u < 8; u++) {
                    int2 r = srt[p + u];
                    w[u] = __int_as_float(r.y);
                    v[u] = __half2float(h[(size_t)(r.x & 0x3FFFF) * HID + lane]);
                }
#pragma unroll
                for (int u = 0; u < 8; u++) a += v[u] * w[u];
            }
            for (; p < pe; ++p) {
                int2 r = srt[p];
                a += __half2float(h[(size_t)(r.x & 0x3FFFF) * HID + lane]) *
                     __int_as_float(r.y);
            }
            acc[it] += a;
        }
        __syncthreads();
    }

    // epilogue: relu(acc + b1) @ W2 via intra-wave shuffle
    int gbase = (t & 63) & ~15;
#pragma unroll
    for (int it = 0; it < NPASS; it++) {
        int node = bkt * BKT_NODES + it * NGRP + grp;
        float hv = fmaxf(acc[it] + bs[lane], 0.f);
        float o = 0.f;
#pragma unroll
        for (int q = 0; q < HID; q++)
            o += __shfl(hv, gbase + q, 64) * wm[q * HID + lane];
        if (node < N_NODES)
            h2[(size_t)node * HID + lane] = __float2half(o);
    }
}

// layer 2 epilogue: out = relu(agg + b2) @ Wd + bd (fp32 out)
__global__ __launch_bounds__(AGG_T) void agg_final_kernel(const __half* __restrict__ h2,
                                                          const int* __restrict__ base2,
                                                          const int2* __restrict__ recs,
                                                          const float* __restrict__ b2,
                                                          const float* __restrict__ Wd,
                                                          const float* __restrict__ bd,
                                                          float* __restrict__ out) {
    __shared__ int2 srt[CAP];
    __shared__ int cnt[BKT_NODES];
    __shared__ int offs[BKT_NODES + 1];
    __shared__ int curs[BKT_NODES];
    __shared__ float wd[HID];
    __shared__ float bs[HID];
    __shared__ float bdv;
    int t = threadIdx.x, bkt = blockIdx.x;
    if (t < HID) { wd[t] = Wd[t]; bs[t] = b2[t]; }
    if (t == 0) bdv = bd[0];
    __syncthreads();

    int beg = base2[bkt];
    int end = base2[bkt + 1];
    int lane = t & 15, grp = t >> 4;

    float acc[NPASS];
#pragma unroll
    for (int i = 0; i < NPASS; i++) acc[i] = 0.f;

    for (int c0 = beg; c0 < end; c0 += CAP) {
        int n = end - c0; if (n > CAP) n = CAP;
        if (t < BKT_NODES) cnt[t] = 0;
        __syncthreads();
        for (int i = t; i < n; i += AGG_T)
            atomicAdd(&cnt[(recs[c0 + i].x >> 18) & (BKT_NODES - 1)], 1);
        __syncthreads();
        if (t == 0) {
            int run = 0;
            for (int k = 0; k < BKT_NODES; k++) { offs[k] = run; run += cnt[k]; }
            offs[BKT_NODES] = run;
        }
        __syncthreads();
        if (t < BKT_NODES) curs[t] = offs[t];
        __syncthreads();
        for (int i = t; i < n; i += AGG_T) {
            int2 r = recs[c0 + i];
            srt[atomicAdd(&curs[(r.x >> 18) & (BKT_NODES - 1)], 1)] = r;
        }
        __syncthreads();

#pragma unroll
        for (int it = 0; it < NPASS; it++) {
            int ld = it * NGRP + grp;
            int pb = offs[ld], pe = offs[ld + 1];
            float a = 0.f;
            int p = pb;
            for (; p + 8 <= pe; p += 8) {
                float v[8], w[8];
#pragma unroll
                for (int u = 0; u < 8; u++) {
                    int2 r = srt[p + u];
                    w[u] = __int_as_float(r.y);
                    v[u] = __half2float(h2[(size_t)(r.x & 0x3FFFF) * HID + lane]);
                }
#pragma unroll
                for (int u = 0; u < 8; u++) a += v[u] * w[u];
            }
            for (; p < pe; ++p) {
                int2 r = srt[p];
                a += __half2float(h2[(size_t)(r.x & 0x3FFFF) * HID + lane]) *
                     __int_as_float(r.y);
            }
            acc[it] += a;
        }
        __syncthreads();
    }

#pragma unroll
    for (int it = 0; it < NPASS; it++) {
        int node = bkt * BKT_NODES + it * NGRP + grp;
        float v = fmaxf(acc[it] + bs[lane], 0.f) * wd[lane];
#pragma unroll
        for (int o = 8; o; o >>= 1) v += __shfl_xor(v, o, 64);
        if (lane == 0 && node < N_NODES) out[node] = v + bdv;
    }
}

// =================== Fallback path (R1, fp32): atomic scatter ===============
__global__ __launch_bounds__(256) void gemm1f_kernel(const float* __restrict__ x,
                                                     const float* __restrict__ W1,
                                                     float* __restrict__ h) {
    __shared__ float w[F_IN * HID];
    int tid = threadIdx.x;
    for (int i = tid; i < F_IN * HID; i += 256) w[i] = W1[i];
    __syncthreads();
    int row = blockIdx.x * 256 + tid;
    if (row >= N_NODES) return;
    float acc[HID];
#pragma unroll
    for (int j = 0; j < HID; j++) acc[j] = 0.f;
    const float4* xr = reinterpret_cast<const float4*>(x + (size_t)row * F_IN);
#pragma unroll 4
    for (int k4 = 0; k4 < F_IN / 4; k4++) {
        float4 xv = xr[k4];
        const float* wr = &w[k4 * 4 * HID];
#pragma unroll
        for (int j = 0; j < HID; j++) acc[j] += xv.x * wr[j];
#pragma unroll
        for (int j = 0; j < HID; j++) acc[j] += xv.y * wr[HID + j];
#pragma unroll
        for (int j = 0; j < HID; j++) acc[j] += xv.z * wr[2 * HID + j];
#pragma unroll
        for (int j = 0; j < HID; j++) acc[j] += xv.w * wr[3 * HID + j];
    }
    float4* hr = reinterpret_cast<float4*>(h + (size_t)row * HID);
#pragma unroll
    for (int q = 0; q < HID / 4; q++)
        hr[q] = make_float4(acc[4 * q], acc[4 * q + 1], acc[4 * q + 2], acc[4 * q + 3]);
}

__global__ __launch_bounds__(256) void scatter_kernel(const float* __restrict__ h,
                                                      const int* __restrict__ src,
                                                      const int* __restrict__ dst,
                                                      const float* __restrict__ ew,
                                                      float* __restrict__ agg,
                                                      int n_edges) {
    long long idx = (long long)blockIdx.x * 256 + threadIdx.x;
    long long total = (long long)n_edges * HID;
    if (idx >= total) return;
    int e = (int)(idx >> 4);
    int j = (int)(idx & (HID - 1));
    float val = h[(size_t)src[e] * HID + j] * ew[e];
    atomicAdd(&agg[(size_t)dst[e] * HID + j], val);
}

__global__ __launch_bounds__(256) void gemm2_kernel(const float* __restrict__ agg,
                                                    const float* __restrict__ b1,
                                                    const float* __restrict__ W2,
                                                    float* __restrict__ h2) {
    __shared__ float w[HID * HID];
    __shared__ float bias[HID];
    int tid = threadIdx.x;
    if (tid < HID * HID) w[tid] = W2[tid];
    if (tid < HID) bias[tid] = b1[tid];
    __syncthreads();
    int row = blockIdx.x * 256 + tid;
    if (row >= N_NODES) return;
    float hv[HID];
    const float4* ar = reinterpret_cast<const float4*>(agg + (size_t)row * HID);
#pragma unroll
    for (int q = 0; q < 4; q++) {
        float4 v = ar[q];
        hv[4 * q + 0] = fmaxf(v.x + bias[4 * q + 0], 0.f);
        hv[4 * q + 1] = fmaxf(v.y + bias[4 * q + 1], 0.f);
        hv[4 * q + 2] = fmaxf(v.z + bias[4 * q + 2], 0.f);
        hv[4 * q + 3] = fmaxf(v.w + bias[4 * q + 3], 0.f);
    }
    float acc[HID];
#pragma unroll
    for (int j = 0; j < HID; j++) acc[j] = 0.f;
#pragma unroll
    for (int k = 0; k < HID; k++) {
        float hk = hv[k];
#pragma unroll
        for (int j = 0; j < HID; j++) acc[j] += hk * w[k * HID + j];
    }
    float4* hr = reinterpret_cast<float4*>(h2 + (size_t)row * HID);
#pragma unroll
    for (int q = 0; q < 4; q++)
        hr[q] = make_float4(acc[4 * q], acc[4 * q + 1], acc[4 * q + 2], acc[4 * q + 3]);
}

__global__ __launch_bounds__(256) void final_kernel(const float* __restrict__ agg,
                                                    const float* __restrict__ b2,
                                                    const float* __restrict__ Wd,
                                                    const float* __restrict__ bd,
                                                    float* __restrict__ out) {
    __shared__ float wd[HID];
    __shared__ float bias[HID];
    __shared__ float bdv;
    int tid = threadIdx.x;
    if (tid < HID) { wd[tid] = Wd[tid]; bias[tid] = b2[tid]; }
    if (tid == 0) bdv = bd[0];
    __syncthreads();
    int row = blockIdx.x * 256 + tid;
    if (row >= N_NODES) return;
    const float4* ar = reinterpret_cast<const float4*>(agg + (size_t)row * HID);
    float acc = bdv;
#pragma unroll
    for (int q = 0; q < 4; q++) {
        float4 v = ar[q];
        acc += fmaxf(v.x + bias[4 * q + 0], 0.f) * wd[4 * q + 0];
        acc += fmaxf(v.y + bias[4 * q + 1], 0.f) * wd[4 * q + 1];
        acc += fmaxf(v.z + bias[4 * q + 2], 0.f) * wd[4 * q + 2];
        acc += fmaxf(v.w + bias[4 * q + 3], 0.f) * wd[4 * q + 3];
    }
    out[row] = acc;
}

extern "C" void kernel_launch(void* const* d_in, const int* in_sizes, int n_in,
                              void* d_out, int out_size, void* d_ws, size_t ws_size,
                              hipStream_t stream) {
    const float* x    = (const float*)d_in[0];
    const int*   esrc = (const int*)d_in[1];
    const int*   edst = (const int*)d_in[2];
    const float* ew   = (const float*)d_in[3];
    const float* W1   = (const float*)d_in[4];
    const float* b1   = (const float*)d_in[5];
    const float* W2   = (const float*)d_in[6];
    const float* b2   = (const float*)d_in[7];
    const float* Wd   = (const float*)d_in[8];
    const float* bd   = (const float*)d_in[9];
    float* out = (float*)d_out;

    int n_edges = in_sizes[1];
    int num_node_blocks = (N_NODES + 255) / 256;

    // ---- workspace layout ----
    size_t hbuf  = (size_t)N_NODES * HID * sizeof(__half);   // 6.4 MB x2
    size_t h2g_b = (((size_t)NF * 4 + 63) / 64) * 64;
    size_t b2_b  = (((size_t)(NF + 1) * 4 + 63) / 64) * 64;
    size_t g2_b  = h2g_b;
    size_t b1_b  = (((size_t)(NC + 1) * 4 + 63) / 64) * 64;
    size_t g1_b  = b1_b;
    size_t recsb = (size_t)n_edges * 8;                      // 51.2 MB x2

    size_t needed = 2 * hbuf + h2g_b + b2_b + g2_b + b1_b + g1_b + 2 * recsb;

    if (ws_size >= needed && n_edges > 0) {
        char* p = (char*)d_ws;
        __half* hA  = (__half*)p;  p += hbuf;
        __half* hB  = (__half*)p;  p += hbuf;
        int* h2g    = (int*)p;     p += h2g_b;
        int* base2  = (int*)p;     p += b2_b;
        int* gcur2  = (int*)p;     p += g2_b;
        int* base1  = (int*)p;     p += b1_b;
        int* gcur1  = (int*)p;     p += g1_b;
        int2* recs1 = (int2*)p;    p += recsb;
        int2* recs2 = (int2*)p;

        int chunk = (n_edges + HBLK - 1) / HBLK;
        int tiles1 = (n_edges + TILE - 1) / TILE;
        int tiles2 = tiles1 + NC;   // covers per-coarse partial tiles

        gemm1_kernel<<<num_node_blocks, 256, 0, stream>>>(x, W1, hA);

        hipMemsetAsync(h2g, 0, h2g_b, stream);
        histboth_kernel<<<HBLK, PBLK, 0, stream>>>(edst, h2g, n_edges, chunk);
        scanall_kernel<<<1, 512, 0, stream>>>(h2g, base2, gcur2, base1, gcur1,
                                              n_edges);
        pass1_kernel<<<tiles1, PBLK, 0, stream>>>(esrc, edst, ew, gcur1, recs1,
                                                  n_edges);
        pass2_kernel<<<tiles2, PBLK, 0, stream>>>(recs1, base1, gcur2, recs2);

        agg_mid_kernel<<<NAGG, AGG_T, 0, stream>>>(hA, base2, recs2, b1, W2, hB);
        agg_final_kernel<<<NAGG, AGG_T, 0, stream>>>(hB, base2, recs2, b2, Wd, bd,
                                                     out);
    } else {
        // Fallback: R1 atomic path (fp32, needs only 2 node buffers)
        size_t node_buf = (size_t)N_NODES * HID * sizeof(float);
        float* bufA = (float*)d_ws;
        float* bufB = (float*)((char*)d_ws + node_buf);
        long long scatter_work = (long long)n_edges * HID;
        int scatter_blocks = (int)((scatter_work + 255) / 256);
        gemm1f_kernel<<<num_node_blocks, 256, 0, stream>>>(x, W1, bufA);
        hipMemsetAsync(bufB, 0, node_buf, stream);
        scatter_kernel<<<scatter_blocks, 256, 0, stream>>>(bufA, esrc, edst, ew, bufB, n_edges);
        gemm2_kernel<<<num_node_blocks, 256, 0, stream>>>(bufB, b1, W2, bufA);
        hipMemsetAsync(bufB, 0, node_buf, stream);
        scatter_kernel<<<scatter_blocks, 256, 0, stream>>>(bufA, esrc, edst, ew, bufB, n_edges);
        final_kernel<<<num_node_blocks, 256, 0, stream>>>(bufB, b2, Wd, bd, out);
    }
}